// Round 2
// baseline (266.121 us; speedup 1.0000x reference)
//
#include <hip/hip_runtime.h>
#include <hip/hip_bf16.h>

typedef float f32x4 __attribute__((ext_vector_type(4)));
typedef short short8 __attribute__((ext_vector_type(8)));

#define LOG2E 1.44269504088896f

__device__ __forceinline__ short f2bf(float f){
  unsigned u = __float_as_uint(f);
  u += 0x7FFFu + ((u >> 16) & 1u);
  return (short)(u >> 16);
}

// ---------------- ws layout (float offsets) ----------------
// pool   [B][64][4]                : 0      (512)
// g      [B][64][4]                : 1024   (512)
// qk     [8][4][4096] (q1s,q2s,k1,k2), q pre-scaled by log2e : 2048 (131072)
// mk     [8][2]                    : 133120 (16)
// vt     bf16 [8][64][4096]        : float offset 134144 (1048576 float slots)
// wT     [ci][tap][co] 64*9*64     : 1182720 (36864)
// ctx2   [B][64][128][128]         : 1219584 (2097152)
#define WS_POOL 0
#define WS_G    1024
#define WS_QK   2048
#define WS_MK   133120
#define WS_VT   134144
#define WS_WT   1182720
#define WS_CTX  1219584

// ---------------- 1. adaptive max pool 128x128 -> 2x2 ----------------
__global__ void k_pool(const float* __restrict__ x, float* __restrict__ pool){
  int bid = blockIdx.x;            // ((b*64+c)*4 + t)
  int t4 = bid & 3; int c = (bid >> 2) & 63; int b = bid >> 8;
  int i = t4 >> 1, j = t4 & 1;
  const float* base = x + (((b*64 + c)*128) + i*64)*128 + j*64;
  int tid = threadIdx.x;
  float m = -3.402823466e38f;
  for (int k = tid; k < 4096; k += 256){
    int r = k >> 6, cc = k & 63;
    m = fmaxf(m, base[r*128 + cc]);
  }
  __shared__ float red[256];
  red[tid] = m; __syncthreads();
  for (int s = 128; s > 0; s >>= 1){
    if (tid < s) red[tid] = fmaxf(red[tid], red[tid + s]);
    __syncthreads();
  }
  if (tid == 0) pool[bid] = red[0];
}

// ---------------- 2. tiny non-local on pooled 2x2 ----------------
__global__ void k_gca(const float* __restrict__ pool,
                      const float* qw, const float* qb,
                      const float* kw, const float* kb,
                      const float* vw, const float* vb,
                      const float* gamma, float* __restrict__ g){
  int b = blockIdx.x; int c = threadIdx.x;   // 64 threads
  __shared__ float P[64][4];
  #pragma unroll
  for (int t = 0; t < 4; t++) P[c][t] = pool[(b*64 + c)*4 + t];
  __syncthreads();
  float q[2][4], kk[2][4];
  #pragma unroll
  for (int i = 0; i < 2; i++)
    #pragma unroll
    for (int n = 0; n < 4; n++){
      float a = qb[i], e = kb[i];
      for (int ci = 0; ci < 64; ci++){
        a += qw[i*64 + ci] * P[ci][n];
        e += kw[i*64 + ci] * P[ci][n];
      }
      q[i][n] = a; kk[i][n] = e;
    }
  float att[4][4];
  #pragma unroll
  for (int n = 0; n < 4; n++){
    float mx = -3.402823466e38f;
    #pragma unroll
    for (int m2 = 0; m2 < 4; m2++){
      att[n][m2] = q[0][n]*kk[0][m2] + q[1][n]*kk[1][m2];
      mx = fmaxf(mx, att[n][m2]);
    }
    float s = 0.f;
    #pragma unroll
    for (int m2 = 0; m2 < 4; m2++){ att[n][m2] = __expf(att[n][m2] - mx); s += att[n][m2]; }
    float inv = 1.f / s;
    #pragma unroll
    for (int m2 = 0; m2 < 4; m2++) att[n][m2] *= inv;
  }
  float v[4];
  #pragma unroll
  for (int m2 = 0; m2 < 4; m2++){
    float a = vb[c];
    for (int ci = 0; ci < 64; ci++) a += vw[c*64 + ci] * P[ci][m2];
    v[m2] = a;
  }
  float gm = gamma[0];
  #pragma unroll
  for (int n = 0; n < 4; n++){
    float o = 0.f;
    #pragma unroll
    for (int m2 = 0; m2 < 4; m2++) o += v[m2] * att[n][m2];
    g[(b*64 + c)*4 + n] = gm*o + P[c][n];
  }
}

// ---------------- 3. per-block q,k (f32) + V (bf16, [c][m]) ----------------
__global__ void k_qkv(const float* __restrict__ x,
                      const float* qw, const float* qb,
                      const float* kw, const float* kb,
                      const float* vw, const float* vb,
                      float* __restrict__ qk, __hip_bfloat16* __restrict__ vt){
  int bid = blockIdx.x;                 // combo*16 + mchunk
  int combo = bid >> 4; int mchunk = bid & 15;
  int b = combo >> 2; int si = (combo >> 1) & 1; int sj = combo & 1;
  int m = mchunk*256 + threadIdx.x;
  int yy = m >> 6, xx = m & 63;
  const float* xp = x + ((b*64)*128 + si*64 + yy)*128 + sj*64 + xx;
  float xr[64];
  #pragma unroll
  for (int ci = 0; ci < 64; ci++) xr[ci] = xp[ci * 16384];
  float q1 = qb[0], q2 = qb[1], k1 = kb[0], k2 = kb[1];
  #pragma unroll
  for (int ci = 0; ci < 64; ci++){
    q1 = fmaf(qw[ci],    xr[ci], q1);
    q2 = fmaf(qw[64+ci], xr[ci], q2);
    k1 = fmaf(kw[ci],    xr[ci], k1);
    k2 = fmaf(kw[64+ci], xr[ci], k2);
  }
  float* qkc = qk + combo*16384;
  qkc[m]         = q1 * LOG2E;
  qkc[4096 + m]  = q2 * LOG2E;
  qkc[8192 + m]  = k1;
  qkc[12288 + m] = k2;
  __hip_bfloat16* vtc = vt + combo*64*4096;
  for (int c = 0; c < 64; c++){
    float a = vb[c];
    const float* wv = vw + c*64;
    #pragma unroll
    for (int ci = 0; ci < 64; ci++) a = fmaf(wv[ci], xr[ci], a);
    vtc[c*4096 + m] = __float2bfloat16(a);
  }
}

// ---------------- 4. max|k1|, max|k2| per combo ----------------
__global__ void k_mk(const float* __restrict__ qk, float* __restrict__ mk){
  int combo = blockIdx.x; int tid = threadIdx.x;
  const float* kp = qk + combo*16384 + 8192;
  float m1 = 0.f, m2 = 0.f;
  for (int i = tid; i < 4096; i += 256){
    m1 = fmaxf(m1, fabsf(kp[i]));
    m2 = fmaxf(m2, fabsf(kp[4096 + i]));
  }
  __shared__ float r1[256], r2[256];
  r1[tid] = m1; r2[tid] = m2; __syncthreads();
  for (int s = 128; s > 0; s >>= 1){
    if (tid < s){ r1[tid] = fmaxf(r1[tid], r1[tid+s]); r2[tid] = fmaxf(r2[tid], r2[tid+s]); }
    __syncthreads();
  }
  if (tid == 0){ mk[combo*2] = r1[0]; mk[combo*2+1] = r2[0]; }
}

// ---------------- 5. fused flash attention (MFMA PV) + gate epilogue ----------------
__global__ __launch_bounds__(512, 2)
void k_flash(const float* __restrict__ x, const float* __restrict__ qk,
             const float* __restrict__ mk, const __hip_bfloat16* __restrict__ vt,
             const float* __restrict__ g, const float* __restrict__ nl_gamma_p,
             float* __restrict__ ctx2){
  int combo = blockIdx.x >> 5; int ntile = blockIdx.x & 31;
  int b = combo >> 2, si = (combo >> 1) & 1, sj = combo & 1;
  int tid = threadIdx.x; int wave = tid >> 6; int lane = tid & 63;
  int l15 = lane & 15, mg = lane >> 4;

  __shared__ __attribute__((aligned(16))) unsigned char vtile[8192];  // [c][m] bf16, XOR-swizzled
  __shared__ __attribute__((aligned(16))) float k1t[64];
  __shared__ __attribute__((aligned(16))) float k2t[64];

  const float* qkc = qk + combo*16384;
  int n = ntile*128 + wave*16 + l15;
  float q1 = qkc[n], q2 = qkc[4096 + n];
  float bound = fabsf(q1)*mk[combo*2] + fabsf(q2)*mk[combo*2+1];

  f32x4 acc[4];
  #pragma unroll
  for (int cg = 0; cg < 4; cg++) acc[cg] = (f32x4){0.f,0.f,0.f,0.f};
  float den = 0.f;

  const __hip_bfloat16* vtc = vt + combo*64*4096;
  int sc = tid >> 3, smb = (tid & 7) * 8;

  for (int mt = 0; mt < 64; mt++){
    __syncthreads();
    // stage V tile (64c x 64m bf16) with XOR swizzle
    f32x4 vv = *(const f32x4*)(vtc + sc*4096 + mt*64 + smb);
    int waddr = (sc << 7) + (smb << 1);
    waddr ^= (sc & 7) << 4;
    *(f32x4*)(vtile + waddr) = vv;
    if (tid < 128){
      if (tid < 64) k1t[tid]      = qkc[8192  + mt*64 + tid];
      else          k2t[tid - 64] = qkc[12288 + mt*64 + tid - 64];
    }
    __syncthreads();

    #pragma unroll
    for (int ks = 0; ks < 2; ks++){
      int mb = ks*32 + mg*8;
      float kv1[8], kv2[8];
      #pragma unroll
      for (int j = 0; j < 8; j++){ kv1[j] = k1t[mb + j]; kv2[j] = k2t[mb + j]; }
      short8 af; float dadd = 0.f;
      #pragma unroll
      for (int j = 0; j < 8; j++){
        float s = fmaf(q1, kv1[j], q2 * kv2[j]) - bound;   // log2 domain
        float e = exp2f(s);
        dadd += e;
        af[j] = f2bf(e);
      }
      den += dadd;
      #pragma unroll
      for (int cg = 0; cg < 4; cg++){
        int c = l15 + (cg << 4);
        int raddr = (c << 7) + (ks << 6) + (mg << 4);
        raddr ^= (c & 7) << 4;
        short8 bf = *(const short8*)(vtile + raddr);
        acc[cg] = __builtin_amdgcn_mfma_f32_16x16x32_bf16(af, bf, acc[cg], 0, 0, 0);
      }
    }
  }

  // full denominator per n (rows spread over mg groups)
  den += __shfl_xor(den, 16, 64);
  den += __shfl_xor(den, 32, 64);
  float inv = 1.f / den;
  float invj[4];
  #pragma unroll
  for (int j = 0; j < 4; j++) invj[j] = __shfl(inv, mg*4 + j, 64);

  float nlg = nl_gamma_p[0];
  int nrow = ntile*128 + wave*16 + mg*4;
  int Y  = si*64 + (nrow >> 6);
  int X0 = sj*64 + (nrow & 63);
  float fy = Y * (1.f/127.f);
  #pragma unroll
  for (int cg = 0; cg < 4; cg++){
    int c = l15 + (cg << 4);
    const float* gp = g + (b*64 + c)*4;
    float g0 = gp[0], g1 = gp[1], g2 = gp[2], g3 = gp[3];
    float top_l = g0 + fy*(g2 - g0);   // lerp in y at x-left
    float top_r = g1 + fy*(g3 - g1);   // lerp in y at x-right
    const float* xrow = x + ((b*64 + c)*128 + Y)*128 + X0;
    f32x4 xv = *(const f32x4*)xrow;
    f32x4 o;
    #pragma unroll
    for (int j = 0; j < 4; j++){
      float val = acc[cg][j] * invj[j];
      float ctx = fmaf(nlg, val, xv[j]);
      float fx = (X0 + j) * (1.f/127.f);
      float gg = top_l + fx*(top_r - top_l);
      float gate = 1.f / (1.f + __expf(-gg));
      o[j] = ctx * gate;
    }
    *(f32x4*)(ctx2 + ((b*64 + c)*128 + Y)*128 + X0) = o;
  }
}

// ---------------- 6. conv weight transpose [co][ci][tap] -> [ci][tap][co] ----------------
__global__ void k_wt(const float* __restrict__ w, float* __restrict__ wt){
  int idx = blockIdx.x*256 + threadIdx.x;   // 36864 total
  int co = idx & 63; int t2 = idx >> 6; int tap = t2 % 9; int ci = t2 / 9;
  wt[idx] = w[(co*64 + ci)*9 + tap];
}

// ---------------- 7. 3x3 conv + bias + BN + gamma residual + relu ----------------
__global__ __launch_bounds__(256, 2)
void k_conv(const float* __restrict__ ctx2, const float* __restrict__ wt,
            const float* __restrict__ cb, const float* __restrict__ bnw,
            const float* __restrict__ bnb, const float* __restrict__ bnm,
            const float* __restrict__ bnv, const float* __restrict__ gp,
            const float* __restrict__ x, float* __restrict__ out){
  int bid = blockIdx.x;              // b*256 + yt*8 + xt  (yt<32, xt<8)
  int xt = bid & 7; int yt = (bid >> 3) & 31; int b = bid >> 8;
  int tid = threadIdx.x; int co = tid & 63; int gq = tid >> 6;
  __shared__ float in_lds[8][6][20];
  __shared__ float wlds[4608];
  float acc[16];
  #pragma unroll
  for (int p = 0; p < 16; p++) acc[p] = 0.f;
  int y = yt*4 + gq;

  for (int ch = 0; ch < 8; ch++){
    __syncthreads();
    for (int idx = tid; idx < 864; idx += 256){
      int ci = idx / 108; int rem = idx - ci*108; int r = rem / 18; int cc = rem - r*18;
      int gy = yt*4 - 1 + r; int gx = xt*16 - 1 + cc;
      float v = 0.f;
      if (gy >= 0 && gy < 128 && gx >= 0 && gx < 128)
        v = ctx2[((b*64 + ch*8 + ci)*128 + gy)*128 + gx];
      in_lds[ci][r][cc] = v;
    }
    for (int idx = tid; idx < 4608; idx += 256) wlds[idx] = wt[ch*4608 + idx];
    __syncthreads();
    for (int ci = 0; ci < 8; ci++){
      #pragma unroll
      for (int dy = 0; dy < 3; dy++){
        float row[18];
        const float* rp = &in_lds[ci][gq + dy][0];
        #pragma unroll
        for (int q = 0; q < 18; q++) row[q] = rp[q];
        #pragma unroll
        for (int dx = 0; dx < 3; dx++){
          float wv = wlds[(ci*9 + dy*3 + dx)*64 + co];
          #pragma unroll
          for (int p = 0; p < 16; p++) acc[p] = fmaf(wv, row[p + dx], acc[p]);
        }
      }
    }
  }
  float scale = bnw[co] * rsqrtf(bnv[co] + 1e-5f);
  float shift = bnb[co] - bnm[co]*scale;
  float cbv = cb[co];
  float gam = gp[0];
  int xbase = xt*16;
  const float* xrow = x + ((b*64 + co)*128 + y)*128 + xbase;
  float* orow = out + ((b*64 + co)*128 + y)*128 + xbase;
  #pragma unroll
  for (int p = 0; p < 16; p++){
    float t = (acc[p] + cbv)*scale + shift;
    float o = fmaf(gam, t, xrow[p]);
    orow[p] = fmaxf(o, 0.f);
  }
}

extern "C" void kernel_launch(void* const* d_in, const int* in_sizes, int n_in,
                              void* d_out, int out_size, void* d_ws, size_t ws_size,
                              hipStream_t stream) {
  const float* x        = (const float*)d_in[0];
  const float* nl_q_w   = (const float*)d_in[1];
  const float* nl_q_b   = (const float*)d_in[2];
  const float* nl_k_w   = (const float*)d_in[3];
  const float* nl_k_b   = (const float*)d_in[4];
  const float* nl_v_w   = (const float*)d_in[5];
  const float* nl_v_b   = (const float*)d_in[6];
  const float* nl_gamma = (const float*)d_in[7];
  const float* gq_w     = (const float*)d_in[8];
  const float* gq_b     = (const float*)d_in[9];
  const float* gk_w     = (const float*)d_in[10];
  const float* gk_b     = (const float*)d_in[11];
  const float* gv_w     = (const float*)d_in[12];
  const float* gv_b     = (const float*)d_in[13];
  const float* g_gamma  = (const float*)d_in[14];
  const float* conv_w   = (const float*)d_in[15];
  const float* conv_b   = (const float*)d_in[16];
  const float* bn_w     = (const float*)d_in[17];
  const float* bn_b     = (const float*)d_in[18];
  const float* bn_mean  = (const float*)d_in[19];
  const float* bn_var   = (const float*)d_in[20];
  const float* gamma    = (const float*)d_in[21];
  float* out = (float*)d_out;

  float* ws = (float*)d_ws;
  float* pool = ws + WS_POOL;
  float* g    = ws + WS_G;
  float* qk   = ws + WS_QK;
  float* mk   = ws + WS_MK;
  __hip_bfloat16* vt = (__hip_bfloat16*)(ws + WS_VT);
  float* wt   = ws + WS_WT;
  float* ctx2 = ws + WS_CTX;

  k_pool<<<512, 256, 0, stream>>>(x, pool);
  k_gca<<<2, 64, 0, stream>>>(pool, gq_w, gq_b, gk_w, gk_b, gv_w, gv_b, g_gamma, g);
  k_qkv<<<128, 256, 0, stream>>>(x, nl_q_w, nl_q_b, nl_k_w, nl_k_b, nl_v_w, nl_v_b, qk, vt);
  k_mk<<<8, 256, 0, stream>>>(qk, mk);
  k_flash<<<256, 512, 0, stream>>>(x, qk, mk, vt, g, nl_gamma, ctx2);
  k_wt<<<144, 256, 0, stream>>>(conv_w, wt);
  k_conv<<<512, 256, 0, stream>>>(ctx2, wt, conv_b, bn_w, bn_b, bn_mean, bn_var, gamma, x, out);
}

// Round 3
// 198.083 us; speedup vs baseline: 1.3435x; 1.3435x over previous
//
#include <hip/hip_runtime.h>
#include <hip/hip_bf16.h>

typedef float f32x4 __attribute__((ext_vector_type(4)));
typedef short short8 __attribute__((ext_vector_type(8)));
typedef unsigned int u32;

#define LOG2E 1.44269504088896f

__device__ __forceinline__ short f2bf(float f){
  unsigned u = __float_as_uint(f);
  u += 0x7FFFu + ((u >> 16) & 1u);
  return (short)(u >> 16);
}

// ---------------- ws layout (float offsets) ----------------
#define WS_POOL 0
#define WS_G    1024
#define WS_QK   2048
#define WS_MK   133120
#define WS_VT   134144
#define WS_WT   1182720
#define WS_CTX  1219584

// ---------------- 1. adaptive max pool 128x128 -> 2x2 (+ mk zero-init) ----
__global__ void k_pool(const float* __restrict__ x, float* __restrict__ pool,
                       u32* __restrict__ mk){
  if (blockIdx.x == 0 && threadIdx.x < 16) mk[threadIdx.x] = 0u;
  int bid = blockIdx.x;            // ((b*64+c)*4 + t)
  int t4 = bid & 3; int c = (bid >> 2) & 63; int b = bid >> 8;
  int i = t4 >> 1, j = t4 & 1;
  const float* base = x + (((b*64 + c)*128) + i*64)*128 + j*64;
  int tid = threadIdx.x;
  float m = -3.402823466e38f;
  for (int k = tid; k < 4096; k += 256){
    int r = k >> 6, cc = k & 63;
    m = fmaxf(m, base[r*128 + cc]);
  }
  __shared__ float red[256];
  red[tid] = m; __syncthreads();
  for (int s = 128; s > 0; s >>= 1){
    if (tid < s) red[tid] = fmaxf(red[tid], red[tid + s]);
    __syncthreads();
  }
  if (tid == 0) pool[bid] = red[0];
}

// ---------------- 2. tiny non-local on pooled 2x2  +  conv-weight transpose
__global__ void k_gca_wt(const float* __restrict__ pool,
                      const float* qw, const float* qb,
                      const float* kw, const float* kb,
                      const float* vw, const float* vb,
                      const float* gamma, float* __restrict__ g,
                      const float* __restrict__ w, float* __restrict__ wt){
  if (blockIdx.x >= 2){
    int idx = (int)(blockIdx.x - 2)*256 + threadIdx.x;   // 36864 total
    if (idx < 36864){
      int co = idx & 63; int t2 = idx >> 6; int tap = t2 % 9; int ci = t2 / 9;
      wt[idx] = w[(co*64 + ci)*9 + tap];
    }
    return;
  }
  int b = blockIdx.x; int c = threadIdx.x;
  __shared__ float P[64][4];
  if (c < 64){
    #pragma unroll
    for (int t = 0; t < 4; t++) P[c][t] = pool[(b*64 + c)*4 + t];
  }
  __syncthreads();
  if (c >= 64) return;
  float q[2][4], kk[2][4];
  #pragma unroll
  for (int i = 0; i < 2; i++)
    #pragma unroll
    for (int n = 0; n < 4; n++){
      float a = qb[i], e = kb[i];
      for (int ci = 0; ci < 64; ci++){
        a += qw[i*64 + ci] * P[ci][n];
        e += kw[i*64 + ci] * P[ci][n];
      }
      q[i][n] = a; kk[i][n] = e;
    }
  float att[4][4];
  #pragma unroll
  for (int n = 0; n < 4; n++){
    float mx = -3.402823466e38f;
    #pragma unroll
    for (int m2 = 0; m2 < 4; m2++){
      att[n][m2] = q[0][n]*kk[0][m2] + q[1][n]*kk[1][m2];
      mx = fmaxf(mx, att[n][m2]);
    }
    float s = 0.f;
    #pragma unroll
    for (int m2 = 0; m2 < 4; m2++){ att[n][m2] = __expf(att[n][m2] - mx); s += att[n][m2]; }
    float inv = 1.f / s;
    #pragma unroll
    for (int m2 = 0; m2 < 4; m2++) att[n][m2] *= inv;
  }
  float v[4];
  #pragma unroll
  for (int m2 = 0; m2 < 4; m2++){
    float a = vb[c];
    for (int ci = 0; ci < 64; ci++) a += vw[c*64 + ci] * P[ci][m2];
    v[m2] = a;
  }
  float gm = gamma[0];
  #pragma unroll
  for (int n = 0; n < 4; n++){
    float o = 0.f;
    #pragma unroll
    for (int m2 = 0; m2 < 4; m2++) o += v[m2] * att[n][m2];
    g[(b*64 + c)*4 + n] = gm*o + P[c][n];
  }
}

// ---------------- 3. per-block q,k (f32) + V (bf16, [c][m]), 4-way c-split,
//                    fused |k| max via atomicMax ----------------
__global__ __launch_bounds__(256, 4)
void k_qkv(const float* __restrict__ x,
           const float* __restrict__ qw, const float* __restrict__ qb,
           const float* __restrict__ kw, const float* __restrict__ kb,
           const float* __restrict__ vw, const float* __restrict__ vb,
           float* __restrict__ qk, __hip_bfloat16* __restrict__ vt,
           u32* __restrict__ mk){
  int bid = blockIdx.x;                 // combo*64 + mchunk*4 + cs
  int cs = bid & 3; int mchunk = (bid >> 2) & 15; int combo = bid >> 6;
  int b = combo >> 2; int si = (combo >> 1) & 1; int sj = combo & 1;
  int tid = threadIdx.x;
  int m = mchunk*256 + tid;
  int yy = m >> 6, xx = m & 63;
  const float* xp = x + ((b*64)*128 + si*64 + yy)*128 + sj*64 + xx;
  float xr[64];
  #pragma unroll
  for (int ci = 0; ci < 64; ci++) xr[ci] = xp[ci * 16384];
  float* qkc = qk + combo*16384;
  __shared__ float r1[256], r2[256];
  if (cs == 0){
    float q1 = qb[0], q2 = qb[1], k1 = kb[0], k2 = kb[1];
    #pragma unroll
    for (int ci = 0; ci < 64; ci++){
      q1 = fmaf(qw[ci],    xr[ci], q1);
      q2 = fmaf(qw[64+ci], xr[ci], q2);
      k1 = fmaf(kw[ci],    xr[ci], k1);
      k2 = fmaf(kw[64+ci], xr[ci], k2);
    }
    qkc[m]         = q1 * LOG2E;
    qkc[4096 + m]  = q2 * LOG2E;
    qkc[8192 + m]  = k1;
    qkc[12288 + m] = k2;
    r1[tid] = fabsf(k1); r2[tid] = fabsf(k2);
    __syncthreads();
    for (int s = 128; s > 0; s >>= 1){
      if (tid < s){ r1[tid] = fmaxf(r1[tid], r1[tid+s]); r2[tid] = fmaxf(r2[tid], r2[tid+s]); }
      __syncthreads();
    }
    if (tid == 0){
      atomicMax(&mk[combo*2],     __float_as_uint(r1[0]));
      atomicMax(&mk[combo*2 + 1], __float_as_uint(r2[0]));
    }
  }
  __hip_bfloat16* vtc = vt + combo*64*4096;
  #pragma unroll 1
  for (int c = cs*16; c < cs*16 + 16; c++){
    float a = vb[c];
    const float* wv = vw + c*64;
    #pragma unroll
    for (int ci = 0; ci < 64; ci++) a = fmaf(wv[ci], xr[ci], a);
    vtc[c*4096 + m] = __float2bfloat16(a);
  }
}

// ---------------- 4. fused flash attention (MFMA PV, dbuf global_load_lds)
//                    + bilinear-sigmoid gate epilogue ----------------
// stage swizzle: LDS granule (row,g) holds V[row][(g^(row&7))*8 ..+7]
#define STAGE(BUFI, MT) do { \
    const __hip_bfloat16* srcb_ = vtc + (MT)*128; \
    _Pragma("unroll") \
    for (int i_ = 0; i_ < 4; i_++){ \
      __builtin_amdgcn_global_load_lds( \
        (const __attribute__((address_space(1))) u32*)(srcb_ + soff[i_]), \
        (__attribute__((address_space(3))) u32*)(&vbuf[BUFI][wave*1024 + i_*4096]), \
        16, 0, 0); \
    } \
  } while(0)

#define CITER(BUFI, MT, DOSTAGE) do { \
    __syncthreads(); \
    if (DOSTAGE) STAGE(1-(BUFI), (MT)+1); \
    const float* kb1_ = qkc + 8192  + (MT)*128 + mg*8; \
    const float* kb2_ = kb1_ + 4096; \
    _Pragma("unroll") \
    for (int ks_ = 0; ks_ < 4; ks_++){ \
      f32x4 ka = *(const f32x4*)(kb1_ + ks_*32); \
      f32x4 kb = *(const f32x4*)(kb1_ + ks_*32 + 4); \
      f32x4 kc = *(const f32x4*)(kb2_ + ks_*32); \
      f32x4 kd = *(const f32x4*)(kb2_ + ks_*32 + 4); \
      short8 af; \
      _Pragma("unroll") \
      for (int j_ = 0; j_ < 4; j_++){ \
        float e0 = exp2f(fmaf(q1, ka[j_], fmaf(q2, kc[j_], nbound))); \
        float e1 = exp2f(fmaf(q1, kb[j_], fmaf(q2, kd[j_], nbound))); \
        den += e0 + e1; \
        af[j_]   = f2bf(e0); \
        af[j_+4] = f2bf(e1); \
      } \
      _Pragma("unroll") \
      for (int cg_ = 0; cg_ < 4; cg_++){ \
        short8 bf = *(const short8*)(&vbuf[BUFI][ra[ks_*4+cg_]]); \
        acc[cg_] = __builtin_amdgcn_mfma_f32_16x16x32_bf16(af, bf, acc[cg_], 0, 0, 0); \
      } \
    } \
  } while(0)

__global__ __launch_bounds__(256, 4)
void k_flash(const float* __restrict__ x, const float* __restrict__ qk,
             const u32* __restrict__ mk, const __hip_bfloat16* __restrict__ vt,
             const float* __restrict__ g, const float* __restrict__ nl_gamma_p,
             float* __restrict__ ctx2){
  int combo = blockIdx.x >> 6; int ntile = blockIdx.x & 63;
  int b = combo >> 2, si = (combo >> 1) & 1, sj = combo & 1;
  int tid = threadIdx.x; int wave = tid >> 6; int lane = tid & 63;
  int l15 = lane & 15, mg = lane >> 4;

  __shared__ __attribute__((aligned(16))) unsigned char vbuf[2][16384];

  const float* qkc = qk + combo*16384;
  int n = ntile*64 + wave*16 + l15;
  float q1 = qkc[n], q2 = qkc[4096 + n];
  float nbound = -(fabsf(q1)*__uint_as_float(mk[combo*2]) +
                   fabsf(q2)*__uint_as_float(mk[combo*2+1]));

  f32x4 acc[4];
  #pragma unroll
  for (int cg = 0; cg < 4; cg++) acc[cg] = (f32x4){0.f,0.f,0.f,0.f};
  float den = 0.f;

  const __hip_bfloat16* vtc = vt + combo*64*4096;

  // swizzled LDS read offsets, hoisted out of the K loop
  int ra[16];
  #pragma unroll
  for (int ks = 0; ks < 4; ks++)
    #pragma unroll
    for (int cg = 0; cg < 4; cg++){
      int c = l15 + (cg << 4);
      ra[ks*4+cg] = (c << 8) + ((((ks<<2)+mg) ^ (c & 7)) << 4);
    }
  // pre-swizzled global source offsets for the 4 staging issues
  int soff[4];
  #pragma unroll
  for (int i = 0; i < 4; i++){
    int gi = i*256 + tid;
    int row = gi >> 4, gg = gi & 15;
    int sg = gg ^ (row & 7);
    soff[i] = row*4096 + sg*8;
  }

  STAGE(0, 0);
  #pragma unroll 1
  for (int mt2 = 0; mt2 < 16; mt2++){
    CITER(0, mt2*2,     1);
    CITER(1, mt2*2 + 1, (mt2 < 15));
  }

  // full denominator per n (rows spread over mg groups)
  den += __shfl_xor(den, 16, 64);
  den += __shfl_xor(den, 32, 64);
  float inv = 1.f / den;
  float invj[4];
  #pragma unroll
  for (int j = 0; j < 4; j++) invj[j] = __shfl(inv, mg*4 + j, 64);

  float nlg = nl_gamma_p[0];
  int Y  = si*64 + ntile;
  int X0 = sj*64 + wave*16 + mg*4;
  float fy = Y * (1.f/127.f);
  #pragma unroll
  for (int cg = 0; cg < 4; cg++){
    int c = l15 + (cg << 4);
    f32x4 gv = *(const f32x4*)(g + (b*64 + c)*4);
    float top_l = gv[0] + fy*(gv[2] - gv[0]);
    float top_r = gv[1] + fy*(gv[3] - gv[1]);
    const float* xrow = x + ((b*64 + c)*128 + Y)*128 + X0;
    f32x4 xv = *(const f32x4*)xrow;
    f32x4 o;
    #pragma unroll
    for (int j = 0; j < 4; j++){
      float val = acc[cg][j] * invj[j];
      float ctx = fmaf(nlg, val, xv[j]);
      float fx = (X0 + j) * (1.f/127.f);
      float gg = top_l + fx*(top_r - top_l);
      float gate = 1.f / (1.f + __expf(-gg));
      o[j] = ctx * gate;
    }
    *(f32x4*)(ctx2 + ((b*64 + c)*128 + Y)*128 + X0) = o;
  }
}

// ---------------- 5. 3x3 conv + bias + BN + gamma residual + relu ---------
__global__ __launch_bounds__(256, 4)
void k_conv(const float* __restrict__ ctx2, const float* __restrict__ wt,
            const float* __restrict__ cb, const float* __restrict__ bnw,
            const float* __restrict__ bnb, const float* __restrict__ bnm,
            const float* __restrict__ bnv, const float* __restrict__ gp,
            const float* __restrict__ x, float* __restrict__ out){
  int bid = blockIdx.x;              // b*512 + yt*8 + xt  (yt<64, xt<8)
  int xt = bid & 7; int yt = (bid >> 3) & 63; int b = bid >> 9;
  int tid = threadIdx.x; int co = tid & 63; int slot = tid >> 6;  // 0..3
  int ry = slot >> 1;            // output row within 2-row tile
  int xh = (slot & 1) * 8;       // col offset (0 / 8)
  __shared__ float in_lds[8][4][20];
  float acc[8];
  #pragma unroll
  for (int p = 0; p < 8; p++) acc[p] = 0.f;

  for (int ch = 0; ch < 8; ch++){
    __syncthreads();
    for (int idx = tid; idx < 576; idx += 256){   // 8ci x 4rows x 18cols
      int ci = idx / 72; int rem = idx - ci*72; int r = rem / 18; int cc = rem - r*18;
      int gy = yt*2 - 1 + r; int gx = xt*16 - 1 + cc;
      float v = 0.f;
      if (gy >= 0 && gy < 128 && gx >= 0 && gx < 128)
        v = ctx2[((b*64 + ch*8 + ci)*128 + gy)*128 + gx];
      in_lds[ci][r][cc] = v;
    }
    __syncthreads();
    #pragma unroll 1
    for (int ci = 0; ci < 8; ci++){
      #pragma unroll
      for (int dy = 0; dy < 3; dy++){
        const float* rp = &in_lds[ci][ry + dy][xh];
        f32x4 va = *(const f32x4*)rp;
        f32x4 vb2 = *(const f32x4*)(rp + 4);
        float r8 = rp[8], r9 = rp[9];
        float rr[10] = {va[0],va[1],va[2],va[3],vb2[0],vb2[1],vb2[2],vb2[3],r8,r9};
        const float* wrow = wt + (((ch*8+ci)*9 + dy*3) << 6) + co;
        float w0 = wrow[0], w1 = wrow[64], w2 = wrow[128];
        #pragma unroll
        for (int p = 0; p < 8; p++)
          acc[p] = fmaf(w2, rr[p+2], fmaf(w1, rr[p+1], fmaf(w0, rr[p], acc[p])));
      }
    }
  }
  float scale = bnw[co] * rsqrtf(bnv[co] + 1e-5f);
  float shift = bnb[co] - bnm[co]*scale;
  float cbv = cb[co]; float gam = gp[0];
  int y = yt*2 + ry; int xb = xt*16 + xh;
  const float* xrow = x + ((b*64 + co)*128 + y)*128 + xb;
  float* orow = out + ((b*64 + co)*128 + y)*128 + xb;
  float ov[8];
  #pragma unroll
  for (int p = 0; p < 8; p++){
    float t = (acc[p] + cbv)*scale + shift;
    ov[p] = fmaxf(fmaf(gam, t, xrow[p]), 0.f);
  }
  f32x4 o0 = {ov[0],ov[1],ov[2],ov[3]};
  f32x4 o1 = {ov[4],ov[5],ov[6],ov[7]};
  *(f32x4*)orow = o0;
  *(f32x4*)(orow + 4) = o1;
}

extern "C" void kernel_launch(void* const* d_in, const int* in_sizes, int n_in,
                              void* d_out, int out_size, void* d_ws, size_t ws_size,
                              hipStream_t stream) {
  const float* x        = (const float*)d_in[0];
  const float* nl_q_w   = (const float*)d_in[1];
  const float* nl_q_b   = (const float*)d_in[2];
  const float* nl_k_w   = (const float*)d_in[3];
  const float* nl_k_b   = (const float*)d_in[4];
  const float* nl_v_w   = (const float*)d_in[5];
  const float* nl_v_b   = (const float*)d_in[6];
  const float* nl_gamma = (const float*)d_in[7];
  const float* gq_w     = (const float*)d_in[8];
  const float* gq_b     = (const float*)d_in[9];
  const float* gk_w     = (const float*)d_in[10];
  const float* gk_b     = (const float*)d_in[11];
  const float* gv_w     = (const float*)d_in[12];
  const float* gv_b     = (const float*)d_in[13];
  const float* g_gamma  = (const float*)d_in[14];
  const float* conv_w   = (const float*)d_in[15];
  const float* conv_b   = (const float*)d_in[16];
  const float* bn_w     = (const float*)d_in[17];
  const float* bn_b     = (const float*)d_in[18];
  const float* bn_mean  = (const float*)d_in[19];
  const float* bn_var   = (const float*)d_in[20];
  const float* gamma    = (const float*)d_in[21];
  float* out = (float*)d_out;

  float* ws = (float*)d_ws;
  float* pool = ws + WS_POOL;
  float* g    = ws + WS_G;
  float* qk   = ws + WS_QK;
  u32*   mk   = (u32*)(ws + WS_MK);
  __hip_bfloat16* vt = (__hip_bfloat16*)(ws + WS_VT);
  float* wt   = ws + WS_WT;
  float* ctx2 = ws + WS_CTX;

  k_pool<<<512, 256, 0, stream>>>(x, pool, mk);
  k_gca_wt<<<146, 256, 0, stream>>>(pool, gq_w, gq_b, gk_w, gk_b, gv_w, gv_b,
                                    g_gamma, g, conv_w, wt);
  k_qkv<<<512, 256, 0, stream>>>(x, nl_q_w, nl_q_b, nl_k_w, nl_k_b,
                                 nl_v_w, nl_v_b, qk, vt, mk);
  k_flash<<<512, 256, 0, stream>>>(x, qk, mk, vt, g, nl_gamma, ctx2);
  k_conv<<<1024, 256, 0, stream>>>(ctx2, wt, conv_b, bn_w, bn_b, bn_mean,
                                   bn_var, gamma, x, out);
}

// Round 6
// 188.663 us; speedup vs baseline: 1.4106x; 1.0499x over previous
//
#include <hip/hip_runtime.h>
#include <hip/hip_bf16.h>

typedef float f32x4 __attribute__((ext_vector_type(4)));
typedef short short8 __attribute__((ext_vector_type(8)));
typedef unsigned int u32;

#define LOG2E 1.44269504088896f

__device__ __forceinline__ short f2bf(float f){
  unsigned u = __float_as_uint(f);
  u += 0x7FFFu + ((u >> 16) & 1u);
  return (short)(u >> 16);
}

// ---------------- ws layout (float offsets) ----------------
#define WS_POOL 0
#define WS_G    1024
#define WS_QK   2048
#define WS_MK   133120
#define WS_VT   134144
#define WS_WT   1182720
#define WS_CTX  1219584
#define WS_PDEN 3316736            // f32 [1024 tiles][64]   (65536)
#define WS_PNUM 3382272            // f32 [1024 tiles][64c][64n] (4194304)
#define WS_SPLIT_BYTES ((size_t)(WS_PNUM + 4194304) * 4)

// ---------------- 1. adaptive max pool 128x128 -> 2x2 (+ mk zero-init) ----
__global__ void k_pool(const float* __restrict__ x, float* __restrict__ pool,
                       u32* __restrict__ mk){
  if (blockIdx.x == 0 && threadIdx.x < 16) mk[threadIdx.x] = 0u;
  int bid = blockIdx.x;            // ((b*64+c)*4 + t)
  int t4 = bid & 3; int c = (bid >> 2) & 63; int b = bid >> 8;
  int i = t4 >> 1, j = t4 & 1;
  const float* base = x + (((b*64 + c)*128) + i*64)*128 + j*64;
  int tid = threadIdx.x;
  float m = -3.402823466e38f;
  for (int k = tid; k < 4096; k += 256){
    int r = k >> 6, cc = k & 63;
    m = fmaxf(m, base[r*128 + cc]);
  }
  __shared__ float red[256];
  red[tid] = m; __syncthreads();
  for (int s = 128; s > 0; s >>= 1){
    if (tid < s) red[tid] = fmaxf(red[tid], red[tid + s]);
    __syncthreads();
  }
  if (tid == 0) pool[bid] = red[0];
}

// ---------------- 2. tiny non-local on pooled 2x2  +  conv-weight transpose
__global__ void k_gca_wt(const float* __restrict__ pool,
                      const float* qw, const float* qb,
                      const float* kw, const float* kb,
                      const float* vw, const float* vb,
                      const float* gamma, float* __restrict__ g,
                      const float* __restrict__ w, float* __restrict__ wt){
  if (blockIdx.x >= 2){
    int idx = (int)(blockIdx.x - 2)*256 + threadIdx.x;   // 36864 total
    if (idx < 36864){
      int co = idx & 63; int t2 = idx >> 6; int tap = t2 % 9; int ci = t2 / 9;
      wt[idx] = w[(co*64 + ci)*9 + tap];
    }
    return;
  }
  int b = blockIdx.x; int c = threadIdx.x;
  __shared__ float P[64][4];
  if (c < 64){
    #pragma unroll
    for (int t = 0; t < 4; t++) P[c][t] = pool[(b*64 + c)*4 + t];
  }
  __syncthreads();
  if (c >= 64) return;
  float q[2][4], kk[2][4];
  #pragma unroll
  for (int i = 0; i < 2; i++)
    #pragma unroll
    for (int n = 0; n < 4; n++){
      float a = qb[i], e = kb[i];
      for (int ci = 0; ci < 64; ci++){
        a += qw[i*64 + ci] * P[ci][n];
        e += kw[i*64 + ci] * P[ci][n];
      }
      q[i][n] = a; kk[i][n] = e;
    }
  float att[4][4];
  #pragma unroll
  for (int n = 0; n < 4; n++){
    float mx = -3.402823466e38f;
    #pragma unroll
    for (int m2 = 0; m2 < 4; m2++){
      att[n][m2] = q[0][n]*kk[0][m2] + q[1][n]*kk[1][m2];
      mx = fmaxf(mx, att[n][m2]);
    }
    float s = 0.f;
    #pragma unroll
    for (int m2 = 0; m2 < 4; m2++){ att[n][m2] = __expf(att[n][m2] - mx); s += att[n][m2]; }
    float inv = 1.f / s;
    #pragma unroll
    for (int m2 = 0; m2 < 4; m2++) att[n][m2] *= inv;
  }
  float v[4];
  #pragma unroll
  for (int m2 = 0; m2 < 4; m2++){
    float a = vb[c];
    for (int ci = 0; ci < 64; ci++) a += vw[c*64 + ci] * P[ci][m2];
    v[m2] = a;
  }
  float gm = gamma[0];
  #pragma unroll
  for (int n = 0; n < 4; n++){
    float o = 0.f;
    #pragma unroll
    for (int m2 = 0; m2 < 4; m2++) o += v[m2] * att[n][m2];
    g[(b*64 + c)*4 + n] = gm*o + P[c][n];
  }
}

// ---------------- 3. per-block q,k (f32) + V (bf16, [c][m]), 4-way c-split,
//                    fused |k| max via atomicMax ----------------
__global__ __launch_bounds__(256, 4)
void k_qkv(const float* __restrict__ x,
           const float* __restrict__ qw, const float* __restrict__ qb,
           const float* __restrict__ kw, const float* __restrict__ kb,
           const float* __restrict__ vw, const float* __restrict__ vb,
           float* __restrict__ qk, __hip_bfloat16* __restrict__ vt,
           u32* __restrict__ mk){
  int bid = blockIdx.x;                 // combo*64 + mchunk*4 + cs
  int cs = bid & 3; int mchunk = (bid >> 2) & 15; int combo = bid >> 6;
  int b = combo >> 2; int si = (combo >> 1) & 1; int sj = combo & 1;
  int tid = threadIdx.x;
  int m = mchunk*256 + tid;
  int yy = m >> 6, xx = m & 63;
  const float* xp = x + ((b*64)*128 + si*64 + yy)*128 + sj*64 + xx;
  float xr[64];
  #pragma unroll
  for (int ci = 0; ci < 64; ci++) xr[ci] = xp[ci * 16384];
  float* qkc = qk + combo*16384;
  __shared__ float r1[256], r2[256];
  if (cs == 0){
    float q1 = qb[0], q2 = qb[1], k1 = kb[0], k2 = kb[1];
    #pragma unroll
    for (int ci = 0; ci < 64; ci++){
      q1 = fmaf(qw[ci],    xr[ci], q1);
      q2 = fmaf(qw[64+ci], xr[ci], q2);
      k1 = fmaf(kw[ci],    xr[ci], k1);
      k2 = fmaf(kw[64+ci], xr[ci], k2);
    }
    qkc[m]         = q1 * LOG2E;
    qkc[4096 + m]  = q2 * LOG2E;
    qkc[8192 + m]  = k1;
    qkc[12288 + m] = k2;
    r1[tid] = fabsf(k1); r2[tid] = fabsf(k2);
    __syncthreads();
    for (int s = 128; s > 0; s >>= 1){
      if (tid < s){ r1[tid] = fmaxf(r1[tid], r1[tid+s]); r2[tid] = fmaxf(r2[tid], r2[tid+s]); }
      __syncthreads();
    }
    if (tid == 0){
      atomicMax(&mk[combo*2],     __float_as_uint(r1[0]));
      atomicMax(&mk[combo*2 + 1], __float_as_uint(r2[0]));
    }
  }
  __hip_bfloat16* vtc = vt + combo*64*4096;
  #pragma unroll 1
  for (int c = cs*16; c < cs*16 + 16; c++){
    float a = vb[c];
    const float* wv = vw + c*64;
    #pragma unroll
    for (int ci = 0; ci < 64; ci++) a = fmaf(wv[ci], xr[ci], a);
    vtc[c*4096 + m] = __float2bfloat16(a);
  }
}

// ---------------- 4. fused flash attention (MFMA PV, dbuf global_load_lds)
// R3-proven core. SPLIT=1: halves of M per block, f32 partials to ws.
// SPLIT=0: single pass + gate epilogue (exact R3 fallback).
#define STAGE(BUFI, MT) do { \
    const __hip_bfloat16* srcb_ = vtc + (MT)*128; \
    _Pragma("unroll") \
    for (int i_ = 0; i_ < 4; i_++){ \
      __builtin_amdgcn_global_load_lds( \
        (const __attribute__((address_space(1))) u32*)(srcb_ + soff[i_]), \
        (__attribute__((address_space(3))) u32*)(&vbuf[BUFI][wave*1024 + i_*4096]), \
        16, 0, 0); \
    } \
  } while(0)

#define CITER(BUFI, MT, DOSTAGE) do { \
    __syncthreads(); \
    if (DOSTAGE) STAGE(1-(BUFI), (MT)+1); \
    const float* kb1_ = qkc + 8192  + (MT)*128 + mg*8; \
    const float* kb2_ = kb1_ + 4096; \
    _Pragma("unroll") \
    for (int ks_ = 0; ks_ < 4; ks_++){ \
      f32x4 ka = *(const f32x4*)(kb1_ + ks_*32); \
      f32x4 kb = *(const f32x4*)(kb1_ + ks_*32 + 4); \
      f32x4 kc = *(const f32x4*)(kb2_ + ks_*32); \
      f32x4 kd = *(const f32x4*)(kb2_ + ks_*32 + 4); \
      short8 af; float dadd = 0.f; \
      _Pragma("unroll") \
      for (int j_ = 0; j_ < 4; j_++){ \
        float e0 = exp2f(fmaf(q1, ka[j_], fmaf(q2, kc[j_], nbound))); \
        float e1 = exp2f(fmaf(q1, kb[j_], fmaf(q2, kd[j_], nbound))); \
        dadd += e0 + e1; \
        af[j_]   = f2bf(e0); \
        af[j_+4] = f2bf(e1); \
      } \
      den += dadd; \
      _Pragma("unroll") \
      for (int cg_ = 0; cg_ < 4; cg_++){ \
        short8 bf = *(const short8*)(&vbuf[BUFI][ra[ks_*4+cg_]]); \
        acc[cg_] = __builtin_amdgcn_mfma_f32_16x16x32_bf16(af, bf, acc[cg_], 0, 0, 0); \
      } \
    } \
  } while(0)

template<int SPLIT>
__global__ __launch_bounds__(256, 4)
void k_flash(const float* __restrict__ x, const float* __restrict__ qk,
             const u32* __restrict__ mk, const __hip_bfloat16* __restrict__ vt,
             const float* __restrict__ g, const float* __restrict__ nl_gamma_p,
             float* __restrict__ ctx2, float* __restrict__ pnum,
             float* __restrict__ pden){
  int combo, ntile, half;
  if (SPLIT){
    combo = blockIdx.x >> 7; int r = blockIdx.x & 127;
    ntile = r >> 1; half = r & 1;
  } else {
    combo = blockIdx.x >> 6; ntile = blockIdx.x & 63; half = 0;
  }
  int b = combo >> 2, si = (combo >> 1) & 1, sj = combo & 1;
  int tid = threadIdx.x; int wave = tid >> 6; int lane = tid & 63;
  int l15 = lane & 15, mg = lane >> 4;

  __shared__ __attribute__((aligned(16))) unsigned char vbuf[2][16384];

  const float* qkc = qk + combo*16384;
  int n = ntile*64 + wave*16 + l15;
  float q1 = qkc[n], q2 = qkc[4096 + n];
  float nbound = -(fabsf(q1)*__uint_as_float(mk[combo*2]) +
                   fabsf(q2)*__uint_as_float(mk[combo*2+1]));

  f32x4 acc[4];
  #pragma unroll
  for (int cg = 0; cg < 4; cg++) acc[cg] = (f32x4){0.f,0.f,0.f,0.f};
  float den = 0.f;

  const __hip_bfloat16* vtc = vt + combo*64*4096;

  // swizzled LDS read offsets, hoisted
  int ra[16];
  #pragma unroll
  for (int ks = 0; ks < 4; ks++)
    #pragma unroll
    for (int cg = 0; cg < 4; cg++){
      int c = l15 + (cg << 4);
      ra[ks*4+cg] = (c << 8) + ((((ks<<2)+mg) ^ (c & 7)) << 4);
    }
  // pre-swizzled global source offsets for staging
  int soff[4];
  #pragma unroll
  for (int i = 0; i < 4; i++){
    int gi = i*256 + tid;
    int row = gi >> 4, gg = gi & 15;
    int sg = gg ^ (row & 7);
    soff[i] = row*4096 + sg*8;
  }

  const int MT0 = SPLIT ? half*16 : 0;
  const int NP  = SPLIT ? 8 : 16;

  STAGE(0, MT0);
  #pragma unroll 1
  for (int mt2 = 0; mt2 < NP; mt2++){
    CITER(0, MT0 + mt2*2,     1);
    CITER(1, MT0 + mt2*2 + 1, (mt2 < NP-1));
  }

  // full (per-half) denominator per n: fold mg groups
  den += __shfl_xor(den, 16, 64);
  den += __shfl_xor(den, 32, 64);

  if (SPLIT){
    int tile = (half*8 + combo)*64 + ntile;
    // num: acc[cg][j] = O_partial[n = wave*16 + mg*4 + j][c = l15 + cg*16]
    #pragma unroll
    for (int cg = 0; cg < 4; cg++){
      int c = l15 + (cg << 4);
      float* pn = pnum + tile*4096 + c*64 + wave*16 + mg*4;
      *(f32x4*)pn = acc[cg];
    }
    // den for n = wave*16 + l15 (replicated over mg); lanes mg==0 store
    if (mg == 0) pden[tile*64 + wave*16 + l15] = den;
  } else {
    float inv = 1.f / den;
    float invj[4];
    #pragma unroll
    for (int j = 0; j < 4; j++) invj[j] = __shfl(inv, mg*4 + j, 64);

    float nlg = nl_gamma_p[0];
    int Y  = si*64 + ntile;
    int X0 = sj*64 + wave*16 + mg*4;
    float fy = Y * (1.f/127.f);
    #pragma unroll
    for (int cg = 0; cg < 4; cg++){
      int c = l15 + (cg << 4);
      f32x4 gv = *(const f32x4*)(g + (b*64 + c)*4);
      float top_l = gv[0] + fy*(gv[2] - gv[0]);
      float top_r = gv[1] + fy*(gv[3] - gv[1]);
      const float* xrow = x + ((b*64 + c)*128 + Y)*128 + X0;
      f32x4 xv = *(const f32x4*)xrow;
      f32x4 o;
      #pragma unroll
      for (int j = 0; j < 4; j++){
        float val = acc[cg][j] * invj[j];
        float ctx = fmaf(nlg, val, xv[j]);
        float fx = (X0 + j) * (1.f/127.f);
        float gg = top_l + fx*(top_r - top_l);
        float gate = 1.f / (1.f + __expf(-gg));
        o[j] = ctx * gate;
      }
      *(f32x4*)(ctx2 + ((b*64 + c)*128 + Y)*128 + X0) = o;
    }
  }
}

// ---------------- 4b. combine halves + normalize + gate ----------------
__global__ __launch_bounds__(256)
void k_combine(const float* __restrict__ pnum, const float* __restrict__ pden,
               const float* __restrict__ x, const float* __restrict__ g,
               const float* __restrict__ nl_gamma_p, float* __restrict__ ctx2){
  int bid = blockIdx.x; int combo = bid >> 6; int nt = bid & 63;
  int b = combo >> 2, si = (combo >> 1) & 1, sj = combo & 1;
  int tid = threadIdx.x; int c = tid >> 2; int nq = tid & 3;
  int tile0 = combo*64 + nt;           // half 0
  int tile1 = tile0 + 512;             // half 1
  const float* n0p = pnum + tile0*4096 + c*64 + nq*16;
  const float* n1p = pnum + tile1*4096 + c*64 + nq*16;
  const float* d0p = pden + tile0*64 + nq*16;
  const float* d1p = pden + tile1*64 + nq*16;
  float inv[16];
  #pragma unroll
  for (int q = 0; q < 4; q++){
    f32x4 a = *(const f32x4*)(d0p + q*4);
    f32x4 bb = *(const f32x4*)(d1p + q*4);
    #pragma unroll
    for (int j = 0; j < 4; j++) inv[q*4+j] = 1.f / fmaxf(a[j] + bb[j], 1e-30f);
  }
  int Y = si*64 + nt; int X0 = sj*64 + nq*16;
  float fy = Y * (1.f/127.f);
  f32x4 gv = *(const f32x4*)(g + (b*64 + c)*4);
  float top_l = gv[0] + fy*(gv[2] - gv[0]);
  float top_r = gv[1] + fy*(gv[3] - gv[1]);
  float nlg = nl_gamma_p[0];
  const float* xrow = x + ((b*64 + c)*128 + Y)*128 + X0;
  float* orow = ctx2 + ((b*64 + c)*128 + Y)*128 + X0;
  #pragma unroll
  for (int q = 0; q < 4; q++){
    f32x4 xv = *(const f32x4*)(xrow + q*4);
    f32x4 nv0 = *(const f32x4*)(n0p + q*4);
    f32x4 nv1 = *(const f32x4*)(n1p + q*4);
    f32x4 o;
    #pragma unroll
    for (int j = 0; j < 4; j++){
      float val = (nv0[j] + nv1[j]) * inv[q*4 + j];
      float ctx = fmaf(nlg, val, xv[j]);
      float fx = (X0 + q*4 + j) * (1.f/127.f);
      float gg = top_l + fx*(top_r - top_l);
      o[j] = ctx / (1.f + __expf(-gg));
    }
    *(f32x4*)(orow + q*4) = o;
  }
}

// ---------------- 5. 3x3 conv + bias + BN + gamma residual + relu ---------
__global__ __launch_bounds__(256, 4)
void k_conv(const float* __restrict__ ctx2, const float* __restrict__ wt,
            const float* __restrict__ cb, const float* __restrict__ bnw,
            const float* __restrict__ bnb, const float* __restrict__ bnm,
            const float* __restrict__ bnv, const float* __restrict__ gp,
            const float* __restrict__ x, float* __restrict__ out){
  int bid = blockIdx.x;              // b*512 + yt*8 + xt  (yt<64, xt<8)
  int xt = bid & 7; int yt = (bid >> 3) & 63; int b = bid >> 9;
  int tid = threadIdx.x; int co = tid & 63; int slot = tid >> 6;  // 0..3
  int ry = slot >> 1;
  int xh = (slot & 1) * 8;
  __shared__ float in_lds[8][4][20];
  float acc[8];
  #pragma unroll
  for (int p = 0; p < 8; p++) acc[p] = 0.f;

  for (int ch = 0; ch < 8; ch++){
    __syncthreads();
    for (int idx = tid; idx < 576; idx += 256){   // 8ci x 4rows x 18cols
      int ci = idx / 72; int rem = idx - ci*72; int r = rem / 18; int cc = rem - r*18;
      int gy = yt*2 - 1 + r; int gx = xt*16 - 1 + cc;
      float v = 0.f;
      if (gy >= 0 && gy < 128 && gx >= 0 && gx < 128)
        v = ctx2[((b*64 + ch*8 + ci)*128 + gy)*128 + gx];
      in_lds[ci][r][cc] = v;
    }
    __syncthreads();
    #pragma unroll 1
    for (int ci = 0; ci < 8; ci++){
      #pragma unroll
      for (int dy = 0; dy < 3; dy++){
        const float* rp = &in_lds[ci][ry + dy][xh];
        f32x4 va = *(const f32x4*)rp;
        f32x4 vb2 = *(const f32x4*)(rp + 4);
        float r8 = rp[8], r9 = rp[9];
        float rr[10] = {va[0],va[1],va[2],va[3],vb2[0],vb2[1],vb2[2],vb2[3],r8,r9};
        const float* wrow = wt + (((ch*8+ci)*9 + dy*3) << 6) + co;
        float w0 = wrow[0], w1 = wrow[64], w2 = wrow[128];
        #pragma unroll
        for (int p = 0; p < 8; p++)
          acc[p] = fmaf(w2, rr[p+2], fmaf(w1, rr[p+1], fmaf(w0, rr[p], acc[p])));
      }
    }
  }
  float scale = bnw[co] * rsqrtf(bnv[co] + 1e-5f);
  float shift = bnb[co] - bnm[co]*scale;
  float cbv = cb[co]; float gam = gp[0];
  int y = yt*2 + ry; int xb = xt*16 + xh;
  const float* xrow = x + ((b*64 + co)*128 + y)*128 + xb;
  float* orow = out + ((b*64 + co)*128 + y)*128 + xb;
  float ov[8];
  #pragma unroll
  for (int p = 0; p < 8; p++){
    float t = (acc[p] + cbv)*scale + shift;
    ov[p] = fmaxf(fmaf(gam, t, xrow[p]), 0.f);
  }
  f32x4 o0 = {ov[0],ov[1],ov[2],ov[3]};
  f32x4 o1 = {ov[4],ov[5],ov[6],ov[7]};
  *(f32x4*)orow = o0;
  *(f32x4*)(orow + 4) = o1;
}

extern "C" void kernel_launch(void* const* d_in, const int* in_sizes, int n_in,
                              void* d_out, int out_size, void* d_ws, size_t ws_size,
                              hipStream_t stream) {
  const float* x        = (const float*)d_in[0];
  const float* nl_q_w   = (const float*)d_in[1];
  const float* nl_q_b   = (const float*)d_in[2];
  const float* nl_k_w   = (const float*)d_in[3];
  const float* nl_k_b   = (const float*)d_in[4];
  const float* nl_v_w   = (const float*)d_in[5];
  const float* nl_v_b   = (const float*)d_in[6];
  const float* nl_gamma = (const float*)d_in[7];
  const float* gq_w     = (const float*)d_in[8];
  const float* gq_b     = (const float*)d_in[9];
  const float* gk_w     = (const float*)d_in[10];
  const float* gk_b     = (const float*)d_in[11];
  const float* gv_w     = (const float*)d_in[12];
  const float* gv_b     = (const float*)d_in[13];
  const float* g_gamma  = (const float*)d_in[14];
  const float* conv_w   = (const float*)d_in[15];
  const float* conv_b   = (const float*)d_in[16];
  const float* bn_w     = (const float*)d_in[17];
  const float* bn_b     = (const float*)d_in[18];
  const float* bn_mean  = (const float*)d_in[19];
  const float* bn_var   = (const float*)d_in[20];
  const float* gamma    = (const float*)d_in[21];
  float* out = (float*)d_out;

  float* ws = (float*)d_ws;
  float* pool = ws + WS_POOL;
  float* g    = ws + WS_G;
  float* qk   = ws + WS_QK;
  u32*   mk   = (u32*)(ws + WS_MK);
  __hip_bfloat16* vt = (__hip_bfloat16*)(ws + WS_VT);
  float* wt   = ws + WS_WT;
  float* ctx2 = ws + WS_CTX;
  float* pden = ws + WS_PDEN;
  float* pnum = ws + WS_PNUM;

  k_pool<<<512, 256, 0, stream>>>(x, pool, mk);
  k_gca_wt<<<146, 256, 0, stream>>>(pool, gq_w, gq_b, gk_w, gk_b, gv_w, gv_b,
                                    g_gamma, g, conv_w, wt);
  k_qkv<<<512, 256, 0, stream>>>(x, nl_q_w, nl_q_b, nl_k_w, nl_k_b,
                                 nl_v_w, nl_v_b, qk, vt, mk);
  if (ws_size >= WS_SPLIT_BYTES){
    k_flash<1><<<1024, 256, 0, stream>>>(x, qk, mk, vt, g, nl_gamma, ctx2, pnum, pden);
    k_combine<<<512, 256, 0, stream>>>(pnum, pden, x, g, nl_gamma, ctx2);
  } else {
    k_flash<0><<<512, 256, 0, stream>>>(x, qk, mk, vt, g, nl_gamma, ctx2, pnum, pden);
  }
  k_conv<<<1024, 256, 0, stream>>>(ctx2, wt, conv_b, bn_w, bn_b, bn_mean,
                                   bn_var, gamma, x, out);
}